// Round 7
// baseline (312.544 us; speedup 1.0000x reference)
//
#include <hip/hip_runtime.h>
#include <math.h>

typedef short short8 __attribute__((ext_vector_type(8)));
typedef float f32x4 __attribute__((ext_vector_type(4)));

constexpr int B_ = 512, T_ = 128, D_ = 128, H_ = 6, E_ = 21, DC_ = 126, F_ = 512;
constexpr float EPS_ = 1e-5f;

__device__ __forceinline__ short f2bf(float f) {
    unsigned u = __float_as_uint(f);
    u = (u + 0x7FFFu + ((u >> 16) & 1u)) >> 16;
    return (short)u;
}
__device__ __forceinline__ unsigned pk2(float lo, float hi) {
    return (unsigned)(unsigned short)f2bf(lo) | ((unsigned)(unsigned short)f2bf(hi) << 16);
}
__device__ __forceinline__ f32x4 mfma16(short8 a, short8 b, f32x4 c) {
    return __builtin_amdgcn_mfma_f32_16x16x32_bf16(a, b, c, 0, 0, 0);
}

// ---------------- prep: bf16-cast + transpose weights ----------------
// WcatT[576][128]: n = w*192 + hd*32 + e (e>=21 zero-padded); W1T[512][128];
// W2T[128][512]; WoT[128][128] (c>=126 zero)
__global__ __launch_bounds__(256) void prep_kernel(
    const float* __restrict__ Wq, const float* __restrict__ Wk, const float* __restrict__ Wv,
    const float* __restrict__ Wo, const float* __restrict__ W1, const float* __restrict__ W2,
    short* __restrict__ WcatT, short* __restrict__ W1T, short* __restrict__ W2T,
    short* __restrict__ WoT) {
    int idx = blockIdx.x * 256 + threadIdx.x;
    if (idx < 73728) {
        int n = idx >> 7, k = idx & 127;
        int w = (n >= 384) ? 2 : (n >= 192 ? 1 : 0);
        int rem = n - w * 192;
        int hd = rem >> 5, e = rem & 31;
        float v = 0.f;
        if (e < 21) {
            const float* src = (w == 0) ? Wq : (w == 1) ? Wk : Wv;
            v = src[(hd * 128 + k) * 21 + e];
        }
        WcatT[idx] = f2bf(v);
    } else if (idx < 139264) {
        int i = idx - 73728;
        int j = i >> 7, d = i & 127;
        W1T[i] = f2bf(W1[d * 512 + j]);
    } else if (idx < 204800) {
        int i = idx - 139264;
        int d = i >> 9, j = i & 511;
        W2T[i] = f2bf(W2[j * 128 + d]);
    } else if (idx < 221184) {
        int i = idx - 204800;
        int d = i >> 7, c = i & 127;
        WoT[i] = f2bf(c < 126 ? Wo[c * 128 + d] : 0.f);
    }
}

// ---------------- mega: LN1 + QKV + causal attention (6 heads) + proj ----------------
// One block per batch b; 512 threads = 8 waves; everything CU-resident.
// LDS: hA 32K + Qh 8K + Kh 8K + VTh 8K + Ps 32K + Os 32K = 120 KiB.
__global__ __launch_bounds__(512, 2) void mega_kernel(
    const float* __restrict__ x, const float* __restrict__ g1, const float* __restrict__ be1,
    const short* __restrict__ WcatT, const short* __restrict__ WoT,
    const float* __restrict__ bo, float* __restrict__ out) {
    __shared__ __align__(16) short hA[T_ * D_];   // [128][128] swz ^((r&7)<<4)
    __shared__ __align__(16) short Qh[T_ * 32];   // [128][32]  swz ^((r&3)<<4)
    __shared__ __align__(16) short Kh[T_ * 32];   // [128][32]  swz ^((r&3)<<4)
    __shared__ __align__(16) short VTh[32 * T_];  // [32][128]  swz ^((e&7)<<4)
    __shared__ __align__(16) short Ps[T_ * T_];   // [128][128] swz ^((t&7)<<4)
    __shared__ __align__(16) short Os[T_ * T_];   // [128][128] swz ^((r&7)<<4)
    int b = blockIdx.x, tid = threadIdx.x;
    const f32x4 fzero = {0.f, 0.f, 0.f, 0.f};
    {   // LN1: 4 threads per row, 128 rows
        int r = tid >> 2, q = tid & 3;
        const float* xr = x + ((size_t)b * T_ + r) * D_ + q * 32;
        float vals[32];
        float sum = 0.f, sq = 0.f;
        #pragma unroll
        for (int i = 0; i < 8; ++i) {
            f32x4 v4 = *(const f32x4*)(xr + i * 4);
            #pragma unroll
            for (int j = 0; j < 4; ++j) { float vv = v4[j]; vals[i*4+j] = vv; sum += vv; sq += vv*vv; }
        }
        sum += __shfl_xor(sum, 1); sum += __shfl_xor(sum, 2);
        sq  += __shfl_xor(sq, 1);  sq  += __shfl_xor(sq, 2);
        float mu = sum * (1.f / 128.f);
        float rs = rsqrtf(sq * (1.f / 128.f) - mu * mu + EPS_);
        char* hb = (char*)hA;
        #pragma unroll
        for (int cc = 0; cc < 4; ++cc) {
            short8 pk;
            #pragma unroll
            for (int j = 0; j < 8; ++j) {
                int d0 = q * 32 + cc * 8 + j;
                pk[j] = f2bf((vals[cc*8+j] - mu) * rs * g1[d0] + be1[d0]);
            }
            int byte = (r * 256 + q * 64 + cc * 16) ^ ((r & 7) << 4);
            *(short8*)(hb + byte) = pk;
        }
        // zero O (swizzle is a per-row bijection on 16B blocks -> linear memset ok)
        short8 z = {0,0,0,0,0,0,0,0};
        char* ob = (char*)Os;
        #pragma unroll
        for (int i = tid; i < 2048; i += 512) *(short8*)(ob + i * 16) = z;
    }
    __syncthreads();
    int lane = tid & 63, wid = tid >> 6;
    int rlo = lane & 15, khi = lane >> 4;
    // per-wave h-fragments for row-tile mt=wid (reused across all heads, Q/K/V)
    short8 hfr[4];
    {
        const char* hb = (const char*)hA;
        int row = wid * 16 + rlo;
        #pragma unroll
        for (int kk = 0; kk < 4; ++kk)
            hfr[kk] = *(const short8*)(hb + ((row * 256 + kk * 64 + khi * 16) ^ ((row & 7) << 4)));
    }
    const float s2 = 0.31482188f;  // (1/sqrt(21)) * log2(e)
    char* qhb = (char*)Qh;
    char* khb = (char*)Kh;
    char* vtb = (char*)VTh;
    char* pb = (char*)Ps;
    char* osb = (char*)Os;
    for (int h = 0; h < 6; ++h) {
        // ---- stage Q/K/V for this head into LDS (wave computes its row-tile) ----
        const short* Wqb = WcatT + (size_t)(h * 32) * 128;
        const short* Wkb = WcatT + (size_t)(192 + h * 32) * 128;
        const short* Wvb = WcatT + (size_t)(384 + h * 32) * 128;
        #pragma unroll
        for (int nq = 0; nq < 2; ++nq) {
            f32x4 qa = fzero, ka = fzero;
            #pragma unroll
            for (int ks = 0; ks < 4; ++ks) {
                short8 wfq = *(const short8*)(Wqb + (size_t)(nq * 16 + rlo) * 128 + ks * 32 + khi * 8);
                short8 wfk = *(const short8*)(Wkb + (size_t)(nq * 16 + rlo) * 128 + ks * 32 + khi * 8);
                qa = mfma16(wfq, hfr[ks], qa);   // D[e][t]: e=nq*16+khi*4+reg, t=wid*16+rlo
                ka = mfma16(wfk, hfr[ks], ka);
            }
            int t = wid * 16 + rlo;
            int byte = (t * 64 + (nq * 16 + khi * 4) * 2) ^ ((t & 3) << 4);
            uint2 qv, kv;
            qv.x = pk2(qa[0], qa[1]); qv.y = pk2(qa[2], qa[3]);
            kv.x = pk2(ka[0], ka[1]); kv.y = pk2(ka[2], ka[3]);
            *(uint2*)(qhb + byte) = qv;
            *(uint2*)(khb + byte) = kv;
        }
        #pragma unroll
        for (int nv = 0; nv < 2; ++nv) {
            f32x4 va = fzero;
            #pragma unroll
            for (int ks = 0; ks < 4; ++ks) {
                short8 wfv = *(const short8*)(Wvb + (size_t)(nv * 16 + rlo) * 128 + ks * 32 + khi * 8);
                va = mfma16(hfr[ks], wfv, va);   // D[t][e]: t=wid*16+khi*4+reg, e=nv*16+rlo
            }
            int e = nv * 16 + rlo;
            int t0 = wid * 16 + khi * 4;
            int byte = (e * 256 + t0 * 2) ^ ((e & 7) << 4);
            uint2 vv;
            vv.x = pk2(va[0], va[1]); vv.y = pk2(va[2], va[3]);
            *(uint2*)(vtb + byte) = vv;
        }
        __syncthreads();
        // ---- QK^T + softmax + PV (verified R6 structure; Q from LDS) ----
        #pragma unroll
        for (int pass = 0; pass < 2; ++pass) {
            int Mt = (pass == 0) ? wid : 7 - wid;  // balanced causal pairing
            int t = Mt * 16 + rlo;
            short8 qf = *(const short8*)(qhb + ((t * 64 + khi * 16) ^ ((t & 3) << 4)));
            f32x4 sacc[8];
            #pragma unroll
            for (int St = 0; St < 8; ++St) {
                sacc[St] = fzero;
                if (St <= Mt) {
                    int srow = St * 16 + rlo;
                    short8 kf = *(const short8*)(khb + ((srow * 64 + khi * 16) ^ ((srow & 3) << 4)));
                    sacc[St] = mfma16(kf, qf, sacc[St]);
                }
            }
            float m = -3e38f;
            #pragma unroll
            for (int St = 0; St < 8; ++St)
                #pragma unroll
                for (int reg = 0; reg < 4; ++reg) {
                    int s = St * 16 + khi * 4 + reg;
                    float v = (s <= t) ? sacc[St][reg] * s2 : -3e38f;
                    sacc[St][reg] = v;
                    m = fmaxf(m, v);
                }
            m = fmaxf(m, __shfl_xor(m, 16));
            m = fmaxf(m, __shfl_xor(m, 32));
            float sum = 0.f;
            #pragma unroll
            for (int St = 0; St < 8; ++St)
                #pragma unroll
                for (int reg = 0; reg < 4; ++reg) {
                    float p = exp2f(sacc[St][reg] - m);
                    sacc[St][reg] = p;
                    sum += p;
                }
            sum += __shfl_xor(sum, 16);
            sum += __shfl_xor(sum, 32);
            float inv = 1.f / sum;
            #pragma unroll
            for (int St = 0; St < 8; ++St) {
                uint2 pv;
                pv.x = pk2(sacc[St][0] * inv, sacc[St][1] * inv);
                pv.y = pk2(sacc[St][2] * inv, sacc[St][3] * inv);
                *(uint2*)(pb + ((t * 256 + St * 32 + khi * 8) ^ ((t & 7) << 4))) = pv;
            }
            // PV (wave-private P rows; same-wave LDS dep)
            f32x4 o0 = fzero, o1 = fzero;
            int kmax = Mt >> 1;
            for (int ks = 0; ks <= kmax; ++ks) {
                int kof = ks * 64 + khi * 16;
                int arow = Mt * 16 + rlo;
                short8 pa = *(const short8*)(pb + ((arow * 256 + kof) ^ ((arow & 7) << 4)));
                short8 b0 = *(const short8*)(vtb + ((rlo * 256 + kof) ^ ((rlo & 7) << 4)));
                short8 b1v = *(const short8*)(vtb + (((16 + rlo) * 256 + kof) ^ (((16 + rlo) & 7) << 4)));
                o0 = mfma16(pa, b0, o0);
                o1 = mfma16(pa, b1v, o1);
            }
            #pragma unroll
            for (int reg = 0; reg < 4; ++reg) {
                int t2 = Mt * 16 + khi * 4 + reg;
                int col = h * 21 + rlo;
                *(short*)(osb + ((t2 * 256 + col * 2) ^ ((t2 & 7) << 4))) = f2bf(o0[reg]);
                if (rlo < 5) {
                    int col1 = h * 21 + 16 + rlo;
                    *(short*)(osb + ((t2 * 256 + col1 * 2) ^ ((t2 & 7) << 4))) = f2bf(o1[reg]);
                }
            }
        }
        __syncthreads();  // protect Qh/Kh/VTh for next head; last iter: O complete
    }
    // ---- proj: out = x + O @ Wo + bo (wave wid owns row-tile mt=wid) ----
    #pragma unroll
    for (int nt = 0; nt < 8; ++nt) {
        int d = nt * 16 + rlo;
        f32x4 acc = fzero;
        #pragma unroll
        for (int ks = 0; ks < 4; ++ks) {
            int arow = wid * 16 + rlo;
            short8 a = *(const short8*)(osb + ((arow * 256 + ks * 64 + khi * 16) ^ ((arow & 7) << 4)));
            short8 bf = *(const short8*)(WoT + (size_t)d * 128 + ks * 32 + khi * 8);
            acc = mfma16(a, bf, acc);
        }
        float bod = bo[d];
        #pragma unroll
        for (int reg = 0; reg < 4; ++reg) {
            int row = wid * 16 + khi * 4 + reg;
            size_t gi = ((size_t)b * T_ + row) * D_ + d;
            out[gi] = x[gi] + bod + acc[reg];
        }
    }
}

// ---------------- fused LN2 + FF: wave-split weights, F through LDS ----------------
__global__ __launch_bounds__(256, 2) void ff_kernel(
    float* __restrict__ out, const float* __restrict__ g2, const float* __restrict__ be2,
    const short* __restrict__ W1T, const float* __restrict__ b1,
    const short* __restrict__ W2T, const float* __restrict__ b2) {
    __shared__ __align__(16) short Hs[64 * 128];  // 16KB swz ^((r&7)<<4)
    __shared__ __align__(16) short Fs[64 * 512];  // 64KB swz ^((t&7)<<4), row stride 1024B
    int tid = threadIdx.x;
    int lane = tid & 63, wid = tid >> 6;
    int rlo = lane & 15, khi = lane >> 4;
    int rowbase = blockIdx.x * 64;
    const f32x4 fzero = {0.f, 0.f, 0.f, 0.f};
    {   // LN2
        int rl = lane >> 2, q = lane & 3;
        int r = wid * 16 + rl;
        const float* xr = out + (size_t)(rowbase + r) * D_ + q * 32;
        float vals[32];
        float sum = 0.f, sq = 0.f;
        #pragma unroll
        for (int i = 0; i < 8; ++i) {
            f32x4 v4 = *(const f32x4*)(xr + i * 4);
            #pragma unroll
            for (int j = 0; j < 4; ++j) { float vv = v4[j]; vals[i*4+j] = vv; sum += vv; sq += vv*vv; }
        }
        sum += __shfl_xor(sum, 1); sum += __shfl_xor(sum, 2);
        sq  += __shfl_xor(sq, 1);  sq  += __shfl_xor(sq, 2);
        float mu = sum * (1.f / 128.f);
        float rs = rsqrtf(sq * (1.f / 128.f) - mu * mu + EPS_);
        char* hb = (char*)Hs;
        #pragma unroll
        for (int cc = 0; cc < 4; ++cc) {
            short8 pk;
            #pragma unroll
            for (int j = 0; j < 8; ++j) {
                int d0 = q * 32 + cc * 8 + j;
                pk[j] = f2bf((vals[cc*8+j] - mu) * rs * g2[d0] + be2[d0]);
            }
            int byte = (r * 256 + q * 64 + cc * 16) ^ ((r & 7) << 4);
            *(short8*)(hb + byte) = pk;
        }
    }
    __syncthreads();
    short8 hfr[4][4];
    {
        const char* hb = (const char*)Hs;
        #pragma unroll
        for (int mt = 0; mt < 4; ++mt)
            #pragma unroll
            for (int kk = 0; kk < 4; ++kk) {
                int t = mt * 16 + rlo;
                hfr[mt][kk] = *(const short8*)(hb + ((t * 256 + kk * 64 + khi * 16) ^ ((t & 7) << 4)));
            }
    }
    {   // FF1 swapped, j-split by wave
        const short* W1w = W1T + (size_t)(wid * 128) * 128;
        char* fb = (char*)Fs;
        #pragma unroll 2
        for (int jt = 0; jt < 8; ++jt) {
            f32x4 fa[4];
            #pragma unroll
            for (int mt = 0; mt < 4; ++mt) fa[mt] = fzero;
            #pragma unroll
            for (int kk = 0; kk < 4; ++kk) {
                short8 wa = *(const short8*)(W1w + (size_t)(jt * 16 + rlo) * 128 + kk * 32 + khi * 8);
                #pragma unroll
                for (int mt = 0; mt < 4; ++mt) fa[mt] = mfma16(wa, hfr[mt][kk], fa[mt]);
            }
            f32x4 bq = *(const f32x4*)(b1 + wid * 128 + jt * 16 + khi * 4);
            #pragma unroll
            for (int mt = 0; mt < 4; ++mt) {
                float v0 = fmaxf(fa[mt][0] + bq[0], 0.f);
                float v1 = fmaxf(fa[mt][1] + bq[1], 0.f);
                float v2 = fmaxf(fa[mt][2] + bq[2], 0.f);
                float v3 = fmaxf(fa[mt][3] + bq[3], 0.f);
                uint2 w;
                w.x = pk2(v0, v1);
                w.y = pk2(v2, v3);
                int t = mt * 16 + rlo;
                int byte = (t * 1024 + wid * 256 + jt * 32 + khi * 8) ^ ((t & 7) << 4);
                *(uint2*)(fb + byte) = w;
            }
        }
    }
    __syncthreads();
    f32x4 oa[4][2];
    #pragma unroll
    for (int mt = 0; mt < 4; ++mt) { oa[mt][0] = fzero; oa[mt][1] = fzero; }
    {   // FF2 d-split by wave
        const char* fb = (const char*)Fs;
        const short* W2w = W2T + (size_t)(wid * 32) * 512;
        #pragma unroll 4
        for (int ks = 0; ks < 16; ++ks) {
            short8 af[4];
            #pragma unroll
            for (int mt = 0; mt < 4; ++mt) {
                int t = mt * 16 + rlo;
                af[mt] = *(const short8*)(fb + ((t * 1024 + ks * 64 + khi * 16) ^ ((t & 7) << 4)));
            }
            #pragma unroll
            for (int nd = 0; nd < 2; ++nd) {
                short8 wf = *(const short8*)(W2w + (size_t)(nd * 16 + rlo) * 512 + ks * 32 + khi * 8);
                #pragma unroll
                for (int mt = 0; mt < 4; ++mt) oa[mt][nd] = mfma16(af[mt], wf, oa[mt][nd]);
            }
        }
    }
    #pragma unroll
    for (int nd = 0; nd < 2; ++nd) {
        int d = wid * 32 + nd * 16 + rlo;
        float b2d = b2[d];
        #pragma unroll
        for (int mt = 0; mt < 4; ++mt) {
            #pragma unroll
            for (int reg = 0; reg < 4; ++reg) {
                int row = rowbase + mt * 16 + khi * 4 + reg;
                size_t gi = (size_t)row * D_ + d;
                out[gi] = out[gi] + b2d + oa[mt][nd][reg];
            }
        }
    }
}

extern "C" void kernel_launch(void* const* d_in, const int* in_sizes, int n_in,
                              void* d_out, int out_size, void* d_ws, size_t ws_size,
                              hipStream_t stream) {
    const float* x   = (const float*)d_in[0];
    const float* Wq  = (const float*)d_in[1];
    const float* Wk  = (const float*)d_in[2];
    const float* Wv  = (const float*)d_in[3];
    const float* Wo  = (const float*)d_in[4];
    const float* bo  = (const float*)d_in[5];
    const float* W1  = (const float*)d_in[6];
    const float* b1  = (const float*)d_in[7];
    const float* W2  = (const float*)d_in[8];
    const float* b2  = (const float*)d_in[9];
    const float* g1  = (const float*)d_in[10];
    const float* be1 = (const float*)d_in[11];
    const float* g2  = (const float*)d_in[12];
    const float* be2 = (const float*)d_in[13];
    float* out = (float*)d_out;

    char* wsb = (char*)d_ws;
    short* WcatT = (short*)(wsb);                 // 147456 B  [576][128]
    short* W1T   = (short*)(wsb + 147456);        // 131072 B
    short* W2T   = (short*)(wsb + 278528);        // 131072 B
    short* WoT   = (short*)(wsb + 409600);        // 32768 B   (total 442368 B)

    prep_kernel<<<864, 256, 0, stream>>>(Wq, Wk, Wv, Wo, W1, W2, WcatT, W1T, W2T, WoT);
    mega_kernel<<<512, 512, 0, stream>>>(x, g1, be1, WcatT, WoT, bo, out);
    ff_kernel<<<1024, 256, 0, stream>>>(out, g2, be2, W1T, b1, W2T, b2);
}

// Round 8
// 267.175 us; speedup vs baseline: 1.1698x; 1.1698x over previous
//
#include <hip/hip_runtime.h>
#include <math.h>

typedef short short8 __attribute__((ext_vector_type(8)));
typedef float f32x4 __attribute__((ext_vector_type(4)));

constexpr int B_ = 512, T_ = 128, D_ = 128, H_ = 6, E_ = 21, DC_ = 126, F_ = 512;
constexpr float EPS_ = 1e-5f;

__device__ __forceinline__ short f2bf(float f) {
    unsigned u = __float_as_uint(f);
    u = (u + 0x7FFFu + ((u >> 16) & 1u)) >> 16;
    return (short)u;
}
__device__ __forceinline__ unsigned pk2(float lo, float hi) {
    return (unsigned)(unsigned short)f2bf(lo) | ((unsigned)(unsigned short)f2bf(hi) << 16);
}
__device__ __forceinline__ f32x4 mfma16(short8 a, short8 b, f32x4 c) {
    return __builtin_amdgcn_mfma_f32_16x16x32_bf16(a, b, c, 0, 0, 0);
}

// ---------------- prep: bf16-cast + transpose weights ----------------
// WcatT[576][128]: n = w*192 + hd*32 + e (e>=21 zero-padded); W1T[512][128];
// W2T[128][512]; WoT[128][128] (c>=126 zero)
__global__ __launch_bounds__(256) void prep_kernel(
    const float* __restrict__ Wq, const float* __restrict__ Wk, const float* __restrict__ Wv,
    const float* __restrict__ Wo, const float* __restrict__ W1, const float* __restrict__ W2,
    short* __restrict__ WcatT, short* __restrict__ W1T, short* __restrict__ W2T,
    short* __restrict__ WoT) {
    int idx = blockIdx.x * 256 + threadIdx.x;
    if (idx < 73728) {
        int n = idx >> 7, k = idx & 127;
        int w = (n >= 384) ? 2 : (n >= 192 ? 1 : 0);
        int rem = n - w * 192;
        int hd = rem >> 5, e = rem & 31;
        float v = 0.f;
        if (e < 21) {
            const float* src = (w == 0) ? Wq : (w == 1) ? Wk : Wv;
            v = src[(hd * 128 + k) * 21 + e];
        }
        WcatT[idx] = f2bf(v);
    } else if (idx < 139264) {
        int i = idx - 73728;
        int j = i >> 7, d = i & 127;
        W1T[i] = f2bf(W1[d * 512 + j]);
    } else if (idx < 204800) {
        int i = idx - 139264;
        int d = i >> 9, j = i & 511;
        W2T[i] = f2bf(W2[j * 128 + d]);
    } else if (idx < 221184) {
        int i = idx - 204800;
        int d = i >> 7, c = i & 127;
        WoT[i] = f2bf(c < 126 ? Wo[c * 128 + d] : 0.f);
    }
}

// ---------------- fused LN1 + QKV v3: 2048 blocks x 256 thr, 32 rows each ----------------
// Wave wid owns n-tiles [wid*9, wid*9+9) over the block's 32 rows (2 M-tiles).
// Q/K tiles (nt<24): swapped mfma -> D[ng][t]; V tiles: normal -> D[t][ng] (VT layout).
// Pad stores (e32>=24) skipped; attn zero-fills those LDS slots.
__global__ __launch_bounds__(256) void qkv_kernel(
    const float* __restrict__ x, const float* __restrict__ g1, const float* __restrict__ be1,
    const short* __restrict__ WcatT,
    short* __restrict__ Qg, short* __restrict__ Kg, short* __restrict__ VTg) {
    __shared__ __align__(16) short hA[32 * 128];  // 8KB, swz ^((r&7)<<4)
    int bid = blockIdx.x;
    int b = bid >> 2, r0 = (bid & 3) * 32;
    int tid = threadIdx.x;
    const f32x4 fzero = {0.f, 0.f, 0.f, 0.f};
    {   // LN1: 8 threads per row, 32 rows
        int r = tid >> 3, q = tid & 7;
        const float* xr = x + ((size_t)b * T_ + r0 + r) * D_ + q * 16;
        float vals[16];
        float sum = 0.f, sq = 0.f;
        #pragma unroll
        for (int i = 0; i < 4; ++i) {
            f32x4 v4 = *(const f32x4*)(xr + i * 4);
            #pragma unroll
            for (int j = 0; j < 4; ++j) { float vv = v4[j]; vals[i*4+j] = vv; sum += vv; sq += vv*vv; }
        }
        sum += __shfl_xor(sum, 1); sum += __shfl_xor(sum, 2); sum += __shfl_xor(sum, 4);
        sq  += __shfl_xor(sq, 1);  sq  += __shfl_xor(sq, 2);  sq  += __shfl_xor(sq, 4);
        float mu = sum * (1.f / 128.f);
        float rs = rsqrtf(sq * (1.f / 128.f) - mu * mu + EPS_);
        char* hb = (char*)hA;
        #pragma unroll
        for (int cc = 0; cc < 2; ++cc) {
            short8 pk;
            #pragma unroll
            for (int j = 0; j < 8; ++j) {
                int d0 = q * 16 + cc * 8 + j;
                pk[j] = f2bf((vals[cc*8+j] - mu) * rs * g1[d0] + be1[d0]);
            }
            int byte = (r * 256 + q * 32 + cc * 16) ^ ((r & 7) << 4);
            *(short8*)(hb + byte) = pk;
        }
    }
    __syncthreads();
    int lane = tid & 63, wid = tid >> 6;
    int rlo = lane & 15, khi = lane >> 4;
    short8 hfr[2][4];
    {
        const char* hb = (const char*)hA;
        #pragma unroll
        for (int m = 0; m < 2; ++m)
            #pragma unroll
            for (int kk = 0; kk < 4; ++kk) {
                int row = m * 16 + rlo;
                hfr[m][kk] = *(const short8*)(hb + ((row * 256 + kk * 64 + khi * 16) ^ ((row & 7) << 4)));
            }
    }
    f32x4 acc[2][9];
    #pragma unroll
    for (int m = 0; m < 2; ++m)
        #pragma unroll
        for (int j = 0; j < 9; ++j) acc[m][j] = fzero;
    #pragma unroll
    for (int ks = 0; ks < 4; ++ks) {
        #pragma unroll
        for (int j = 0; j < 9; ++j) {
            int nt = wid * 9 + j;
            short8 wf = *(const short8*)(WcatT + (size_t)(nt * 16 + rlo) * 128 + ks * 32 + khi * 8);
            if (nt < 24) {
                #pragma unroll
                for (int m = 0; m < 2; ++m) acc[m][j] = mfma16(wf, hfr[m][ks], acc[m][j]);
            } else {
                #pragma unroll
                for (int m = 0; m < 2; ++m) acc[m][j] = mfma16(hfr[m][ks], wf, acc[m][j]);
            }
        }
    }
    // epilogue: packed 8B stores; skip pad columns/rows (e32 >= 24)
    #pragma unroll
    for (int j = 0; j < 9; ++j) {
        int nt = wid * 9 + j;
        bool odd = (nt & 1) != 0;
        if (nt < 24) {   // Q or K: D[ng][t]
            int ng = nt * 16 + khi * 4;
            int w = (ng >= 192) ? 1 : 0;
            int hd = (ng >> 5) - w * 6;
            int e32 = ng & 31;
            if (!(odd && khi >= 2)) {
                short* dst = (w ? Kg : Qg) + (((size_t)b * 6 + hd) * 128) * 32 + e32;
                #pragma unroll
                for (int m = 0; m < 2; ++m) {
                    int t = r0 + m * 16 + rlo;
                    uint2 pv;
                    pv.x = pk2(acc[m][j][0], acc[m][j][1]);
                    pv.y = pk2(acc[m][j][2], acc[m][j][3]);
                    *(uint2*)(dst + (size_t)t * 32) = pv;
                }
            }
        } else {         // V: D[t][ng] -> VT layout
            int ng = nt * 16 + rlo;
            int hd = (ng >> 5) - 12;
            int e32 = ng & 31;
            if (!(odd && rlo >= 8)) {
                short* dst = VTg + (((size_t)b * 6 + hd) * 32 + e32) * 128;
                #pragma unroll
                for (int m = 0; m < 2; ++m) {
                    int t0 = r0 + m * 16 + khi * 4;
                    uint2 pv;
                    pv.x = pk2(acc[m][j][0], acc[m][j][1]);
                    pv.y = pk2(acc[m][j][2], acc[m][j][3]);
                    *(uint2*)(dst + t0) = pv;
                }
            }
        }
    }
}

// ---------------- causal attention: swapped QK^T, group softmax (R6-verified) ----------------
__global__ __launch_bounds__(256) void attn_kernel(
    const short* __restrict__ Qg, const short* __restrict__ Kg, const short* __restrict__ VTg,
    short* __restrict__ Obf) {
    __shared__ __align__(16) short Ks[T_ * 32];   // [128][32]  swz ^((r&3)<<4)
    __shared__ __align__(16) short VTs[32 * T_];  // [32][128]  swz ^((e&7)<<4)
    __shared__ __align__(16) short Ps[T_ * T_];   // [128][128] swz ^((t&7)<<4)
    int h = blockIdx.x, b = blockIdx.y, tid = threadIdx.x;
    size_t bh = (size_t)b * 6 + h;
    const f32x4 fzero = {0.f, 0.f, 0.f, 0.f};
    {   // staging: e>=24 slots zero-filled (not written by qkv)
        char* kb = (char*)Ks;
        const short* Ksrc = Kg + bh * (128 * 32);
        const short8 z8 = {0,0,0,0,0,0,0,0};
        #pragma unroll
        for (int c = tid; c < 512; c += 256) {
            int r = c >> 2, cc = c & 3;
            short8 kv = (cc < 3) ? *(const short8*)(Ksrc + r * 32 + cc * 8) : z8;
            *(short8*)(kb + ((r * 64 + cc * 16) ^ ((r & 3) << 4))) = kv;
        }
        char* vb = (char*)VTs;
        const short* Vsrc = VTg + bh * (32 * 128);
        #pragma unroll
        for (int c = tid; c < 512; c += 256) {
            int e = c >> 4, cc = c & 15;
            short8 vv = (e < 24) ? *(const short8*)(Vsrc + e * 128 + cc * 8) : z8;
            *(short8*)(vb + ((e * 256 + cc * 16) ^ ((e & 7) << 4))) = vv;
        }
    }
    __syncthreads();
    int lane = tid & 63, wid = tid >> 6;
    int rlo = lane & 15, khi = lane >> 4;
    const float s2 = 0.31482188f;  // (1/sqrt(21)) * log2(e)
    const char* kb = (const char*)Ks;
    const char* vb = (const char*)VTs;
    char* pb = (char*)Ps;
    #pragma unroll
    for (int pass = 0; pass < 2; ++pass) {
        int Mt = (pass == 0) ? wid : 7 - wid;  // balanced causal pairing; P rows disjoint
        int t = Mt * 16 + rlo;
        short8 qf = *(const short8*)(Qg + (bh * 128 + t) * 32 + khi * 8);
        f32x4 sacc[8];
        #pragma unroll
        for (int St = 0; St < 8; ++St) {
            sacc[St] = fzero;
            if (St <= Mt) {
                int srow = St * 16 + rlo;
                short8 kf = *(const short8*)(kb + ((srow * 64 + khi * 16) ^ ((srow & 3) << 4)));
                sacc[St] = mfma16(kf, qf, sacc[St]);
            }
        }
        // masked softmax: lane-local partials, reduce across khi group (xor 16,32)
        float m = -3e38f;
        #pragma unroll
        for (int St = 0; St < 8; ++St)
            #pragma unroll
            for (int reg = 0; reg < 4; ++reg) {
                int s = St * 16 + khi * 4 + reg;
                float v = (s <= t) ? sacc[St][reg] * s2 : -3e38f;
                sacc[St][reg] = v;
                m = fmaxf(m, v);
            }
        m = fmaxf(m, __shfl_xor(m, 16));
        m = fmaxf(m, __shfl_xor(m, 32));
        float sum = 0.f;
        #pragma unroll
        for (int St = 0; St < 8; ++St)
            #pragma unroll
            for (int reg = 0; reg < 4; ++reg) {
                float p = exp2f(sacc[St][reg] - m);
                sacc[St][reg] = p;
                sum += p;
            }
        sum += __shfl_xor(sum, 16);
        sum += __shfl_xor(sum, 32);
        float inv = 1.f / sum;
        #pragma unroll
        for (int St = 0; St < 8; ++St) {
            uint2 pv;
            pv.x = pk2(sacc[St][0] * inv, sacc[St][1] * inv);
            pv.y = pk2(sacc[St][2] * inv, sacc[St][3] * inv);
            *(uint2*)(pb + ((t * 256 + St * 32 + khi * 8) ^ ((t & 7) << 4))) = pv;
        }
        // PV (wave-private P rows; same-wave LDS dep)
        f32x4 o0 = fzero, o1 = fzero;
        int kmax = Mt >> 1;
        for (int ks = 0; ks <= kmax; ++ks) {
            int kof = ks * 64 + khi * 16;
            int arow = Mt * 16 + rlo;
            short8 pa = *(const short8*)(pb + ((arow * 256 + kof) ^ ((arow & 7) << 4)));
            short8 b0 = *(const short8*)(vb + ((rlo * 256 + kof) ^ ((rlo & 7) << 4)));
            short8 b1v = *(const short8*)(vb + (((16 + rlo) * 256 + kof) ^ (((16 + rlo) & 7) << 4)));
            o0 = mfma16(pa, b0, o0);
            o1 = mfma16(pa, b1v, o1);
        }
        #pragma unroll
        for (int reg = 0; reg < 4; ++reg) {
            int t2 = Mt * 16 + khi * 4 + reg;
            Obf[((size_t)b * 128 + t2) * 128 + h * 21 + rlo] = f2bf(o0[reg]);
            if (rlo < 5)
                Obf[((size_t)b * 128 + t2) * 128 + h * 21 + 16 + rlo] = f2bf(o1[reg]);
        }
    }
}

// ---------------- proj: x + o @ Wo + bo -> out (fp32), 64 rows/block ----------------
__global__ __launch_bounds__(256) void proj_kernel(
    const float* __restrict__ x, const short* __restrict__ Obf, const short* __restrict__ WoT,
    const float* __restrict__ bo, float* __restrict__ out) {
    __shared__ __align__(16) short Os[64 * 128];  // swz ^((r&7)<<4)
    int r0 = blockIdx.x * 64, tid = threadIdx.x;
    const f32x4 fzero = {0.f, 0.f, 0.f, 0.f};
    char* ob = (char*)Os;
    for (int c = tid; c < 1024; c += 256) {
        int r = c >> 4, cc = c & 15;
        short8 v = *(const short8*)(Obf + (size_t)(r0 + r) * 128 + cc * 8);
        if (cc == 15) { v[6] = 0; v[7] = 0; }  // cols 126,127 pad
        int byte = (r * 256 + cc * 16) ^ ((r & 7) << 4);
        *(short8*)(ob + byte) = v;
    }
    __syncthreads();
    int lane = tid & 63, mt = tid >> 6;
    int rlo = lane & 15, khi = lane >> 4;
    #pragma unroll
    for (int nt = 0; nt < 8; ++nt) {
        int d = nt * 16 + rlo;
        f32x4 acc = fzero;
        #pragma unroll
        for (int ks = 0; ks < 4; ++ks) {
            int arow = mt * 16 + rlo;
            short8 a = *(const short8*)(ob + ((arow * 256 + ks * 64 + khi * 16) ^ ((arow & 7) << 4)));
            short8 bf = *(const short8*)(WoT + (size_t)d * 128 + ks * 32 + khi * 8);
            acc = mfma16(a, bf, acc);
        }
        float bod = bo[d];
        #pragma unroll
        for (int reg = 0; reg < 4; ++reg) {
            int row = r0 + mt * 16 + khi * 4 + reg;
            out[(size_t)row * 128 + d] = x[(size_t)row * 128 + d] + bod + acc[reg];
        }
    }
}

// ---------------- fused LN2 + FF: wave-split weights, F through LDS ----------------
__global__ __launch_bounds__(256, 2) void ff_kernel(
    float* __restrict__ out, const float* __restrict__ g2, const float* __restrict__ be2,
    const short* __restrict__ W1T, const float* __restrict__ b1,
    const short* __restrict__ W2T, const float* __restrict__ b2) {
    __shared__ __align__(16) short Hs[64 * 128];  // 16KB swz ^((r&7)<<4)
    __shared__ __align__(16) short Fs[64 * 512];  // 64KB swz ^((t&7)<<4), row stride 1024B
    int tid = threadIdx.x;
    int lane = tid & 63, wid = tid >> 6;
    int rlo = lane & 15, khi = lane >> 4;
    int rowbase = blockIdx.x * 64;
    const f32x4 fzero = {0.f, 0.f, 0.f, 0.f};
    {   // LN2
        int rl = lane >> 2, q = lane & 3;
        int r = wid * 16 + rl;
        const float* xr = out + (size_t)(rowbase + r) * D_ + q * 32;
        float vals[32];
        float sum = 0.f, sq = 0.f;
        #pragma unroll
        for (int i = 0; i < 8; ++i) {
            f32x4 v4 = *(const f32x4*)(xr + i * 4);
            #pragma unroll
            for (int j = 0; j < 4; ++j) { float vv = v4[j]; vals[i*4+j] = vv; sum += vv; sq += vv*vv; }
        }
        sum += __shfl_xor(sum, 1); sum += __shfl_xor(sum, 2);
        sq  += __shfl_xor(sq, 1);  sq  += __shfl_xor(sq, 2);
        float mu = sum * (1.f / 128.f);
        float rs = rsqrtf(sq * (1.f / 128.f) - mu * mu + EPS_);
        char* hb = (char*)Hs;
        #pragma unroll
        for (int cc = 0; cc < 4; ++cc) {
            short8 pk;
            #pragma unroll
            for (int j = 0; j < 8; ++j) {
                int d0 = q * 32 + cc * 8 + j;
                pk[j] = f2bf((vals[cc*8+j] - mu) * rs * g2[d0] + be2[d0]);
            }
            int byte = (r * 256 + q * 64 + cc * 16) ^ ((r & 7) << 4);
            *(short8*)(hb + byte) = pk;
        }
    }
    __syncthreads();
    short8 hfr[4][4];
    {
        const char* hb = (const char*)Hs;
        #pragma unroll
        for (int mt = 0; mt < 4; ++mt)
            #pragma unroll
            for (int kk = 0; kk < 4; ++kk) {
                int t = mt * 16 + rlo;
                hfr[mt][kk] = *(const short8*)(hb + ((t * 256 + kk * 64 + khi * 16) ^ ((t & 7) << 4)));
            }
    }
    {   // FF1 swapped, j-split by wave
        const short* W1w = W1T + (size_t)(wid * 128) * 128;
        char* fb = (char*)Fs;
        #pragma unroll 2
        for (int jt = 0; jt < 8; ++jt) {
            f32x4 fa[4];
            #pragma unroll
            for (int mt = 0; mt < 4; ++mt) fa[mt] = fzero;
            #pragma unroll
            for (int kk = 0; kk < 4; ++kk) {
                short8 wa = *(const short8*)(W1w + (size_t)(jt * 16 + rlo) * 128 + kk * 32 + khi * 8);
                #pragma unroll
                for (int mt = 0; mt < 4; ++mt) fa[mt] = mfma16(wa, hfr[mt][kk], fa[mt]);
            }
            f32x4 bq = *(const f32x4*)(b1 + wid * 128 + jt * 16 + khi * 4);
            #pragma unroll
            for (int mt = 0; mt < 4; ++mt) {
                float v0 = fmaxf(fa[mt][0] + bq[0], 0.f);
                float v1 = fmaxf(fa[mt][1] + bq[1], 0.f);
                float v2 = fmaxf(fa[mt][2] + bq[2], 0.f);
                float v3 = fmaxf(fa[mt][3] + bq[3], 0.f);
                uint2 w;
                w.x = pk2(v0, v1);
                w.y = pk2(v2, v3);
                int t = mt * 16 + rlo;
                int byte = (t * 1024 + wid * 256 + jt * 32 + khi * 8) ^ ((t & 7) << 4);
                *(uint2*)(fb + byte) = w;
            }
        }
    }
    __syncthreads();
    f32x4 oa[4][2];
    #pragma unroll
    for (int mt = 0; mt < 4; ++mt) { oa[mt][0] = fzero; oa[mt][1] = fzero; }
    {   // FF2 d-split by wave
        const char* fb = (const char*)Fs;
        const short* W2w = W2T + (size_t)(wid * 32) * 512;
        #pragma unroll 4
        for (int ks = 0; ks < 16; ++ks) {
            short8 af[4];
            #pragma unroll
            for (int mt = 0; mt < 4; ++mt) {
                int t = mt * 16 + rlo;
                af[mt] = *(const short8*)(fb + ((t * 1024 + ks * 64 + khi * 16) ^ ((t & 7) << 4)));
            }
            #pragma unroll
            for (int nd = 0; nd < 2; ++nd) {
                short8 wf = *(const short8*)(W2w + (size_t)(nd * 16 + rlo) * 512 + ks * 32 + khi * 8);
                #pragma unroll
                for (int mt = 0; mt < 4; ++mt) oa[mt][nd] = mfma16(af[mt], wf, oa[mt][nd]);
            }
        }
    }
    #pragma unroll
    for (int nd = 0; nd < 2; ++nd) {
        int d = wid * 32 + nd * 16 + rlo;
        float b2d = b2[d];
        #pragma unroll
        for (int mt = 0; mt < 4; ++mt) {
            #pragma unroll
            for (int reg = 0; reg < 4; ++reg) {
                int row = rowbase + mt * 16 + khi * 4 + reg;
                size_t gi = (size_t)row * D_ + d;
                out[gi] = out[gi] + b2d + oa[mt][nd][reg];
            }
        }
    }
}

extern "C" void kernel_launch(void* const* d_in, const int* in_sizes, int n_in,
                              void* d_out, int out_size, void* d_ws, size_t ws_size,
                              hipStream_t stream) {
    const float* x   = (const float*)d_in[0];
    const float* Wq  = (const float*)d_in[1];
    const float* Wk  = (const float*)d_in[2];
    const float* Wv  = (const float*)d_in[3];
    const float* Wo  = (const float*)d_in[4];
    const float* bo  = (const float*)d_in[5];
    const float* W1  = (const float*)d_in[6];
    const float* b1  = (const float*)d_in[7];
    const float* W2  = (const float*)d_in[8];
    const float* b2  = (const float*)d_in[9];
    const float* g1  = (const float*)d_in[10];
    const float* be1 = (const float*)d_in[11];
    const float* g2  = (const float*)d_in[12];
    const float* be2 = (const float*)d_in[13];
    float* out = (float*)d_out;

    char* wsb = (char*)d_ws;
    short* WcatT = (short*)(wsb);                 // 147456 B  [576][128]
    short* W1T   = (short*)(wsb + 147456);        // 131072 B
    short* W2T   = (short*)(wsb + 278528);        // 131072 B
    short* WoT   = (short*)(wsb + 409600);        // 32768 B
    short* Qg    = (short*)(wsb + 442368);        // 25165824 B [b][h][128][32]
    short* Kg    = (short*)(wsb + 25608192);      // 25165824 B
    short* VTg   = (short*)(wsb + 50774016);      // 25165824 B [b][h][32][128]
    short* Obf   = (short*)(wsb + 75939840);      // 16777216 B (total ~92.7 MB)

    prep_kernel<<<864, 256, 0, stream>>>(Wq, Wk, Wv, Wo, W1, W2, WcatT, W1T, W2T, WoT);
    qkv_kernel<<<2048, 256, 0, stream>>>(x, g1, be1, WcatT, Qg, Kg, VTg);
    attn_kernel<<<dim3(6, 512), 256, 0, stream>>>(Qg, Kg, VTg, Obf);
    proj_kernel<<<1024, 256, 0, stream>>>(x, Obf, WoT, bo, out);
    ff_kernel<<<1024, 256, 0, stream>>>(out, g2, be2, W1T, b1, W2T, b2);
}